// Round 3
// baseline (477.785 us; speedup 1.0000x reference)
//
#include <hip/hip_runtime.h>

// ---------------- problem constants ----------------
#define T_TOK 8192      // B*S tokens
#define H_DIM 2048
#define E_NUM 8
#define N1 528          // gate 256 + up 256 + loraA 16 rows in W1
#define K2 288          // down 256 + loraB 16 + zero-pad 16 (K of stage B)

typedef __bf16 bf16x8 __attribute__((ext_vector_type(8)));
typedef float  f32x4  __attribute__((ext_vector_type(4)));
typedef unsigned short u16;
typedef u16 u16x8 __attribute__((ext_vector_type(8)));

__device__ __forceinline__ u16 f2bf(float f) {
    unsigned u = __builtin_bit_cast(unsigned, f);
    u += 0x7fffu + ((u >> 16) & 1u);          // round-to-nearest-even
    return (u16)(u >> 16);
}
__device__ __forceinline__ float bf2f(u16 s) {
    return __builtin_bit_cast(float, (unsigned)s << 16);
}

// async global->LDS, 16B per lane. LDS dest must be wave-uniform base + lane*16.
__device__ __forceinline__ void gl16(const u16* g, u16* l) {
    __builtin_amdgcn_global_load_lds(
        (__attribute__((address_space(1))) void*)g,
        (__attribute__((address_space(3))) void*)l,
        16, 0, 0);
}

// ---------------- Gt: transpose router weight G[H][E] -> Gt[E][H] ----------------
__global__ __launch_bounds__(256) void k_gt(const float* __restrict__ G, float* __restrict__ Gt) {
    int idx = blockIdx.x * 256 + threadIdx.x;     // 16384
    int h = idx >> 3, e = idx & 7;
    Gt[e * H_DIM + h] = G[idx];
}

// ---------------- router: fp32 logits via coalesced Gt, softmax, top-2; emits bf16 x ----------------
__global__ __launch_bounds__(256) void k_router(
    const float* __restrict__ x, const float* __restrict__ Gt,
    u16* __restrict__ xbf, int* __restrict__ counts,
    int* __restrict__ list, float* __restrict__ wlist,
    int2* __restrict__ e01, int2* __restrict__ p01, float2* __restrict__ w01)
{
    int lane = threadIdx.x & 63;
    int t = blockIdx.x * 4 + (threadIdx.x >> 6);   // one wave per token
    const float4* xr = reinterpret_cast<const float4*>(x + (size_t)t * H_DIM);
    const float4* g4 = reinterpret_cast<const float4*>(Gt);
    ushort4* xb4 = reinterpret_cast<ushort4*>(xbf + (size_t)t * H_DIM);
    float acc[8];
#pragma unroll
    for (int e = 0; e < 8; e++) acc[e] = 0.f;
#pragma unroll
    for (int i = 0; i < 8; i++) {
        int h4 = i * 64 + lane;
        float4 xv = xr[h4];
        ushort4 o; o.x = f2bf(xv.x); o.y = f2bf(xv.y); o.z = f2bf(xv.z); o.w = f2bf(xv.w);
        xb4[h4] = o;
#pragma unroll
        for (int e = 0; e < 8; e++) {
            float4 gv = g4[e * (H_DIM / 4) + h4];   // coalesced, L2-hot
            acc[e] += xv.x * gv.x + xv.y * gv.y + xv.z * gv.z + xv.w * gv.w;
        }
    }
#pragma unroll
    for (int e = 0; e < 8; e++) {
#pragma unroll
        for (int off = 32; off >= 1; off >>= 1)
            acc[e] += __shfl_xor(acc[e], off);
    }
    if (lane == 0) {
        float m = acc[0];
#pragma unroll
        for (int e = 1; e < 8; e++) m = fmaxf(m, acc[e]);
        float p[8], s = 0.f;
#pragma unroll
        for (int e = 0; e < 8; e++) { p[e] = __expf(acc[e] - m); s += p[e]; }
        float inv = 1.f / s;
        int i0 = 0; float b0 = acc[0];
#pragma unroll
        for (int e = 1; e < 8; e++) if (acc[e] > b0) { b0 = acc[e]; i0 = e; }
        int i1 = -1; float b1 = -3.4e38f;
#pragma unroll
        for (int e = 0; e < 8; e++) if (e != i0 && acc[e] > b1) { b1 = acc[e]; i1 = e; }
        float w0 = p[i0] * inv, w1 = p[i1] * inv;
        int pos0 = atomicAdd(&counts[i0], 1);
        int pos1 = atomicAdd(&counts[i1], 1);
        list[i0 * T_TOK + pos0] = t; wlist[i0 * T_TOK + pos0] = w0;
        list[i1 * T_TOK + pos1] = t; wlist[i1 * T_TOK + pos1] = w1;
        e01[t] = make_int2(i0, i1);
        p01[t] = make_int2(pos0, pos1);
        w01[t] = make_float2(w0, w1);
    }
}

__global__ void k_base(const int* __restrict__ counts, int* __restrict__ base) {
    int b = 0;
    for (int e = 0; e < 8; e++) { base[e] = b; b += counts[e]; }
    base[8] = b;
}

// ---------------- weight prep: W1[e] = [gate;up;loraA] bf16, K=2048 ----------------
__global__ __launch_bounds__(256) void k_w1(
    const float* __restrict__ gate_w, const float* __restrict__ up_w,
    const float* __restrict__ lora_A, u16* __restrict__ W1)
{
    int idx = (blockIdx.x * 256 + threadIdx.x) * 4;
    int e = idx / (N1 * H_DIM);
    int rem = idx - e * (N1 * H_DIM);
    int r = rem / H_DIM;
    int h = rem - r * H_DIM;
    const float* src;
    if (r < 256)      src = gate_w + ((size_t)(e * 256 + r) * H_DIM + h);
    else if (r < 512) src = up_w   + ((size_t)(e * 256 + (r - 256)) * H_DIM + h);
    else              src = lora_A + ((size_t)(e * 16 + (r - 512)) * H_DIM + h);
    float4 v = *reinterpret_cast<const float4*>(src);
    ushort4 o; o.x = f2bf(v.x); o.y = f2bf(v.y); o.z = f2bf(v.z); o.w = f2bf(v.w);
    *reinterpret_cast<ushort4*>(W1 + idx) = o;
}

// ---------------- weight prep: W2[e][h] = [down(256)|loraB(16)|0(16)] bf16 ----------------
__global__ __launch_bounds__(256) void k_w2(
    const float* __restrict__ down_w, const float* __restrict__ lora_B,
    u16* __restrict__ W2)
{
    int idx = (blockIdx.x * 256 + threadIdx.x) * 4;
    int e = idx / (H_DIM * K2);
    int rem = idx - e * (H_DIM * K2);
    int h = rem / K2;
    int c = rem - h * K2;
    ushort4 o;
    if (c < 256) {
        float4 v = *reinterpret_cast<const float4*>(down_w + ((size_t)(e * H_DIM + h) * 256 + c));
        o.x = f2bf(v.x); o.y = f2bf(v.y); o.z = f2bf(v.z); o.w = f2bf(v.w);
    } else if (c < 272) {
        float4 v = *reinterpret_cast<const float4*>(lora_B + ((size_t)(e * H_DIM + h) * 16 + (c - 256)));
        o.x = f2bf(v.x); o.y = f2bf(v.y); o.z = f2bf(v.z); o.w = f2bf(v.w);
    } else {
        o.x = 0; o.y = 0; o.z = 0; o.w = 0;
    }
    *reinterpret_cast<ushort4*>(W2 + idx) = o;
}

// ---------------- stage A: m97-style 128x128 tile, LDS staged, silu fused ----------------
// grid.x = 2048 linear: s = bid&31 (e = s>>2, nt = s&3), mt = bid>>5 (0..63)
// B-tile rows (128) = [gate f0-31][up f0-31][gate f32-63][up f32-63], f rel to nt*64.
// XOR chunk swizzle: LDS[row][c] holds global chunk c^(row&7); read chunk j at c=j^(row&7).
__global__ __launch_bounds__(256, 2) void k_stage_a(
    const u16* __restrict__ xbf, const u16* __restrict__ W1,
    const int* __restrict__ counts, const int* __restrict__ base,
    const int* __restrict__ list, u16* __restrict__ ascr)
{
    int bid = blockIdx.x;
    int s = bid & 31, mt = bid >> 5;
    int e = s >> 2, nt = s & 3;
    int ne = counts[e];
    int m0 = mt * 128;
    if (m0 >= ne) return;

    __shared__ u16 lA[128 * 64];   // 16 KB
    __shared__ u16 lB[128 * 64];   // 16 KB
    __shared__ u16 lL[16 * 64];    // 2 KB (loraA rows)

    const int L = threadIdx.x;
    int w = L >> 6, l = L & 63;
    int wm = w >> 1, wn = w & 1;
    int r16 = l & 15, q = l >> 4;
    int sr = L >> 3, sc = L & 7;           // staging: row-within-group, chunk

    const u16* w1e = W1 + (size_t)e * N1 * H_DIM;
    const u16* aptr[4]; const u16* bptr[4];
#pragma unroll
    for (int a = 0; a < 4; a++) {
        int row = a * 32 + sr;
        int pos = m0 + row; if (pos >= ne) pos = ne - 1;
        int t = list[e * T_TOK + pos];
        aptr[a] = xbf + (size_t)t * H_DIM + (sc ^ (sr & 7)) * 8;
        int w1row = (a & 1) * 256 + nt * 64 + (a >> 1) * 32 + sr;
        bptr[a] = w1e + (size_t)w1row * H_DIM + (sc ^ (sr & 7)) * 8;
    }
    bool lora_blk = (nt == 0);
    const u16* lptr = nullptr;
    if (lora_blk && w < 2) {
        int row = L >> 3;                  // 0..15
        lptr = w1e + (size_t)(512 + row) * H_DIM + (sc ^ (row & 7)) * 8;
    }
    bool lora_wave = lora_blk && (wn == 0);

    f32x4 acc[4][4] = {};                  // [mi][ni]; ni 0,1 gate / 2,3 up
    f32x4 accl[4] = {};

    for (int r = 0; r < 32; ++r) {
        int k0 = r * 64;
        __syncthreads();
#pragma unroll
        for (int a = 0; a < 4; a++) {
            gl16(aptr[a] + k0, &lA[(a * 256 + L) * 8]);
            gl16(bptr[a] + k0, &lB[(a * 256 + L) * 8]);
        }
        if (lora_blk && w < 2) gl16(lptr + k0, &lL[L * 8]);
        __syncthreads();
#pragma unroll
        for (int ks = 0; ks < 2; ks++) {
            bf16x8 af[4], bfr[4];
#pragma unroll
            for (int mi = 0; mi < 4; mi++) {
                int row = wm * 64 + mi * 16 + r16;
                af[mi] = *reinterpret_cast<const bf16x8*>(&lA[(row * 8 + ((ks * 4 + q) ^ (row & 7))) * 8]);
            }
#pragma unroll
            for (int ni = 0; ni < 4; ni++) {
                int rb = wn * 64 + ni * 16 + r16;
                bfr[ni] = *reinterpret_cast<const bf16x8*>(&lB[(rb * 8 + ((ks * 4 + q) ^ (rb & 7))) * 8]);
            }
#pragma unroll
            for (int mi = 0; mi < 4; mi++)
#pragma unroll
                for (int ni = 0; ni < 4; ni++)
                    acc[mi][ni] = __builtin_amdgcn_mfma_f32_16x16x32_bf16(af[mi], bfr[ni], acc[mi][ni], 0, 0, 0);
            if (lora_wave) {
                bf16x8 lf = *reinterpret_cast<const bf16x8*>(&lL[(r16 * 8 + ((ks * 4 + q) ^ (r16 & 7))) * 8]);
#pragma unroll
                for (int mi = 0; mi < 4; mi++)
                    accl[mi] = __builtin_amdgcn_mfma_f32_16x16x32_bf16(af[mi], lf, accl[mi], 0, 0, 0);
            }
        }
    }

    int eb = base[e];
#pragma unroll
    for (int mi = 0; mi < 4; mi++)
#pragma unroll
        for (int reg = 0; reg < 4; reg++) {
            int pos = m0 + wm * 64 + mi * 16 + q * 4 + reg;
            if (pos >= ne) continue;
            size_t ro = (size_t)(eb + pos) * K2;
#pragma unroll
            for (int ni = 0; ni < 2; ni++) {
                float g = acc[mi][ni][reg], u = acc[mi][ni + 2][reg];
                float val = g / (1.f + __expf(-g)) * u;          // silu(g)*u
                ascr[ro + nt * 64 + wn * 32 + ni * 16 + r16] = f2bf(val);
            }
            if (lora_wave) {
                ascr[ro + 256 + r16] = f2bf(accl[mi][reg]);
                ascr[ro + 272 + r16] = 0;                        // K-pad
            }
        }
}

// ---------------- stage B: 128x128 tile, K=288 in 3 rounds of BK=96 ----------------
// grid.x = 8192 linear: s = bid&127 (e = s>>4, ntile = s&15), mt = bid>>7 (0..63)
// chunk swizzle on low 2 bits: LDS[row][c] holds global chunk (c&~3)|((c&3)^(row&3)).
template <bool USE_Y>
__global__ __launch_bounds__(256, 2) void k_stage_b(
    const u16* __restrict__ ascr, const u16* __restrict__ W2,
    const int* __restrict__ counts, const int* __restrict__ base,
    const int* __restrict__ list, const float* __restrict__ wlist,
    u16* __restrict__ Y, float* __restrict__ out)
{
    int bid = blockIdx.x;
    int s = bid & 127, mt = bid >> 7;
    int e = s >> 4, ntile = s & 15;
    int ne = counts[e];
    int m0 = mt * 128;
    if (m0 >= ne) return;
    int n0 = ntile * 128;

    __shared__ u16 lA[128 * 96];   // 24 KB
    __shared__ u16 lB[128 * 96];   // 24 KB

    const int L = threadIdx.x;
    int w = L >> 6, l = L & 63;
    int wm = w >> 1, wn = w & 1;
    int r16 = l & 15, q = l >> 4;
    int eb = base[e];

    const u16* w2e = W2 + (size_t)e * H_DIM * K2;
    const u16* aptr[6]; const u16* bptr[6];
#pragma unroll
    for (int a = 0; a < 6; a++) {
        int g = a * 256 + L;                 // 0..1535 chunks (128 rows x 12)
        int row = g / 12, c = g - row * 12;
        int csw = (c & ~3) | ((c & 3) ^ (row & 3));
        int pos = m0 + row; if (pos >= ne) pos = ne - 1;
        aptr[a] = ascr + (size_t)(eb + pos) * K2 + csw * 8;
        bptr[a] = w2e + (size_t)(n0 + row) * K2 + csw * 8;
    }

    f32x4 acc[4][4] = {};
    for (int r = 0; r < 3; ++r) {
        int k0 = r * 96;
        __syncthreads();
#pragma unroll
        for (int a = 0; a < 6; a++) {
            gl16(aptr[a] + k0, &lA[(a * 256 + L) * 8]);
            gl16(bptr[a] + k0, &lB[(a * 256 + L) * 8]);
        }
        __syncthreads();
#pragma unroll
        for (int ks = 0; ks < 3; ks++) {
            bf16x8 af[4], bfr[4];
#pragma unroll
            for (int mi = 0; mi < 4; mi++) {
                int row = wm * 64 + mi * 16 + r16;
                int j = ks * 4 + (q ^ (row & 3));
                af[mi] = *reinterpret_cast<const bf16x8*>(&lA[(row * 12 + j) * 8]);
            }
#pragma unroll
            for (int ni = 0; ni < 4; ni++) {
                int rb = wn * 64 + ni * 16 + r16;
                int j = ks * 4 + (q ^ (rb & 3));
                bfr[ni] = *reinterpret_cast<const bf16x8*>(&lB[(rb * 12 + j) * 8]);
            }
#pragma unroll
            for (int mi = 0; mi < 4; mi++)
#pragma unroll
                for (int ni = 0; ni < 4; ni++)
                    acc[mi][ni] = __builtin_amdgcn_mfma_f32_16x16x32_bf16(af[mi], bfr[ni], acc[mi][ni], 0, 0, 0);
        }
    }

#pragma unroll
    for (int mi = 0; mi < 4; mi++)
#pragma unroll
        for (int reg = 0; reg < 4; reg++) {
            int pos = m0 + wm * 64 + mi * 16 + q * 4 + reg;
            if (pos >= ne) continue;
            if (USE_Y) {
                size_t ro = (size_t)(eb + pos) * H_DIM;
#pragma unroll
                for (int ni = 0; ni < 4; ni++)
                    Y[ro + n0 + wn * 64 + ni * 16 + r16] = f2bf(acc[mi][ni][reg]);
            } else {
                int t = list[e * T_TOK + pos];
                float wt = wlist[e * T_TOK + pos];
#pragma unroll
                for (int ni = 0; ni < 4; ni++)
                    atomicAdd(out + (size_t)t * H_DIM + n0 + wn * 64 + ni * 16 + r16, wt * acc[mi][ni][reg]);
            }
        }
}

// ---------------- combine: out[t] = w0*Y[s0] + w1*Y[s1] ----------------
__global__ __launch_bounds__(256) void k_combine(
    const u16* __restrict__ Y, const int* __restrict__ base,
    const int2* __restrict__ e01, const int2* __restrict__ p01,
    const float2* __restrict__ w01, float* __restrict__ out)
{
    int t = blockIdx.x;
    int c = threadIdx.x * 8;
    int2 es = e01[t]; int2 ps = p01[t]; float2 ws = w01[t];
    size_t s0 = (size_t)(base[es.x] + ps.x) * H_DIM + c;
    size_t s1 = (size_t)(base[es.y] + ps.y) * H_DIM + c;
    u16x8 a = *reinterpret_cast<const u16x8*>(Y + s0);
    u16x8 b = *reinterpret_cast<const u16x8*>(Y + s1);
    float* op = out + (size_t)t * H_DIM + c;
    float4 o0, o1;
    o0.x = ws.x * bf2f(a[0]) + ws.y * bf2f(b[0]);
    o0.y = ws.x * bf2f(a[1]) + ws.y * bf2f(b[1]);
    o0.z = ws.x * bf2f(a[2]) + ws.y * bf2f(b[2]);
    o0.w = ws.x * bf2f(a[3]) + ws.y * bf2f(b[3]);
    o1.x = ws.x * bf2f(a[4]) + ws.y * bf2f(b[4]);
    o1.y = ws.x * bf2f(a[5]) + ws.y * bf2f(b[5]);
    o1.z = ws.x * bf2f(a[6]) + ws.y * bf2f(b[6]);
    o1.w = ws.x * bf2f(a[7]) + ws.y * bf2f(b[7]);
    *reinterpret_cast<float4*>(op) = o0;
    *reinterpret_cast<float4*>(op + 4) = o1;
}

extern "C" void kernel_launch(void* const* d_in, const int* in_sizes, int n_in,
                              void* d_out, int out_size, void* d_ws, size_t ws_size,
                              hipStream_t stream)
{
    const float* x      = (const float*)d_in[0];
    const float* G      = (const float*)d_in[1];
    const float* gate_w = (const float*)d_in[2];
    const float* up_w   = (const float*)d_in[3];
    const float* down_w = (const float*)d_in[4];
    const float* lora_A = (const float*)d_in[5];
    const float* lora_B = (const float*)d_in[6];
    float* out = (float*)d_out;

    char* ws = (char*)d_ws;
    size_t o = 0;
    auto carve = [&](size_t bytes) -> char* {
        char* p = ws + o;
        o = (o + bytes + 255) & ~(size_t)255;
        return p;
    };
    int*    counts = (int*)carve(8 * 4);
    int*    ebase  = (int*)carve(9 * 4);
    float*  Gt     = (float*)carve((size_t)E_NUM * H_DIM * 4);
    int2*   e01    = (int2*)carve((size_t)T_TOK * 8);
    int2*   p01    = (int2*)carve((size_t)T_TOK * 8);
    float2* w01    = (float2*)carve((size_t)T_TOK * 8);
    int*    list   = (int*)carve((size_t)E_NUM * T_TOK * 4);
    float*  wlist  = (float*)carve((size_t)E_NUM * T_TOK * 4);
    u16*    xbf    = (u16*)carve((size_t)T_TOK * H_DIM * 2);
    u16*    W1     = (u16*)carve((size_t)E_NUM * N1 * H_DIM * 2);
    u16*    W2     = (u16*)carve((size_t)E_NUM * H_DIM * K2 * 2);
    u16*    ascr   = (u16*)carve((size_t)2 * T_TOK * K2 * 2);
    u16*    Y      = (u16*)carve((size_t)2 * T_TOK * H_DIM * 2);
    bool use_y = (ws_size >= o);

    hipMemsetAsync(counts, 0, 32, stream);
    k_gt<<<(E_NUM * H_DIM) / 256, 256, 0, stream>>>(G, Gt);
    k_router<<<T_TOK / 4, 256, 0, stream>>>(x, Gt, xbf, counts, list, wlist, e01, p01, w01);
    k_base<<<1, 1, 0, stream>>>(counts, ebase);
    k_w1<<<(E_NUM * N1 * H_DIM / 4) / 256, 256, 0, stream>>>(gate_w, up_w, lora_A, W1);
    k_w2<<<(E_NUM * H_DIM * K2 / 4) / 256, 256, 0, stream>>>(down_w, lora_B, W2);
    k_stage_a<<<2048, 256, 0, stream>>>(xbf, W1, counts, ebase, list, ascr);
    if (use_y) {
        k_stage_b<true><<<8192, 256, 0, stream>>>(ascr, W2, counts, ebase, list, wlist, Y, out);
        k_combine<<<T_TOK, 256, 0, stream>>>(Y, ebase, e01, p01, w01, out);
    } else {
        hipMemsetAsync(out, 0, (size_t)out_size * 4, stream);
        k_stage_b<false><<<8192, 256, 0, stream>>>(ascr, W2, counts, ebase, list, wlist, Y, out);
    }
}

// Round 4
// 317.557 us; speedup vs baseline: 1.5046x; 1.5046x over previous
//
#include <hip/hip_runtime.h>

// ---------------- problem constants ----------------
#define T_TOK 8192      // B*S tokens
#define H_DIM 2048
#define E_NUM 8
#define N1 528          // gate 256 + up 256 + loraA 16 rows in W1
#define K2 288          // down 256 + loraB 16 + zero-pad 16 (K of stage B)
#define CSTR 16         // counts[] stride in ints (64B: one line per expert)

typedef __bf16 bf16x8 __attribute__((ext_vector_type(8)));
typedef float  f32x4  __attribute__((ext_vector_type(4)));
typedef unsigned short u16;
typedef u16 u16x8 __attribute__((ext_vector_type(8)));
typedef unsigned long long u64;

__device__ __forceinline__ u16 f2bf(float f) {
    unsigned u = __builtin_bit_cast(unsigned, f);
    u += 0x7fffu + ((u >> 16) & 1u);          // round-to-nearest-even
    return (u16)(u >> 16);
}
__device__ __forceinline__ float bf2f(u16 s) {
    return __builtin_bit_cast(float, (unsigned)s << 16);
}

// async global->LDS, 16B per lane. LDS dest must be wave-uniform base + lane*16.
__device__ __forceinline__ void gl16(const u16* g, u16* l) {
    __builtin_amdgcn_global_load_lds(
        (__attribute__((address_space(1))) void*)g,
        (__attribute__((address_space(3))) void*)l,
        16, 0, 0);
}

// ---------------- Gt: transpose router weight G[H][E] -> Gt[E][H] ----------------
__global__ __launch_bounds__(256) void k_gt(const float* __restrict__ G, float* __restrict__ Gt) {
    int idx = blockIdx.x * 256 + threadIdx.x;     // 16384
    int h = idx >> 3, e = idx & 7;
    Gt[e * H_DIM + h] = G[idx];
}

// ---------------- router: fp32 logits, softmax, top-2. NO atomics. emits bf16 x ----------------
__global__ __launch_bounds__(256) void k_router(
    const float* __restrict__ x, const float* __restrict__ Gt,
    u16* __restrict__ xbf, int2* __restrict__ e01, float2* __restrict__ w01)
{
    int lane = threadIdx.x & 63;
    int t = blockIdx.x * 4 + (threadIdx.x >> 6);   // one wave per token
    const float4* xr = reinterpret_cast<const float4*>(x + (size_t)t * H_DIM);
    const float4* g4 = reinterpret_cast<const float4*>(Gt);
    ushort4* xb4 = reinterpret_cast<ushort4*>(xbf + (size_t)t * H_DIM);
    float acc[8];
#pragma unroll
    for (int e = 0; e < 8; e++) acc[e] = 0.f;
#pragma unroll
    for (int i = 0; i < 8; i++) {
        int h4 = i * 64 + lane;
        float4 xv = xr[h4];
        ushort4 o; o.x = f2bf(xv.x); o.y = f2bf(xv.y); o.z = f2bf(xv.z); o.w = f2bf(xv.w);
        xb4[h4] = o;
#pragma unroll
        for (int e = 0; e < 8; e++) {
            float4 gv = g4[e * (H_DIM / 4) + h4];   // coalesced, L2-hot
            acc[e] += xv.x * gv.x + xv.y * gv.y + xv.z * gv.z + xv.w * gv.w;
        }
    }
#pragma unroll
    for (int e = 0; e < 8; e++) {
#pragma unroll
        for (int off = 32; off >= 1; off >>= 1)
            acc[e] += __shfl_xor(acc[e], off);
    }
    if (lane == 0) {
        float m = acc[0];
#pragma unroll
        for (int e = 1; e < 8; e++) m = fmaxf(m, acc[e]);
        float p[8], s = 0.f;
#pragma unroll
        for (int e = 0; e < 8; e++) { p[e] = __expf(acc[e] - m); s += p[e]; }
        float inv = 1.f / s;
        int i0 = 0; float b0 = acc[0];
#pragma unroll
        for (int e = 1; e < 8; e++) if (acc[e] > b0) { b0 = acc[e]; i0 = e; }
        int i1 = -1; float b1 = -3.4e38f;
#pragma unroll
        for (int e = 0; e < 8; e++) if (e != i0 && acc[e] > b1) { b1 = acc[e]; i1 = e; }
        e01[t] = make_int2(i0, i1);
        w01[t] = make_float2(p[i0] * inv, p[i1] * inv);
    }
}

// ---------------- count/scatter: ballot histogram, 8 atomics/block ----------------
// 32 blocks x 256 threads, token-per-thread. Builds list/wlist/p01.
__global__ __launch_bounds__(256) void k_count(
    const int2* __restrict__ e01, const float2* __restrict__ w01,
    int* __restrict__ counts, int* __restrict__ list, float* __restrict__ wlist,
    int2* __restrict__ p01)
{
    __shared__ int wcnt[4][8];
    __shared__ int gbase[8];
    int tid = threadIdx.x;
    int t = blockIdx.x * 256 + tid;
    int lane = tid & 63, w = tid >> 6;
    int2 es = e01[t];
    float2 ws = w01[t];
    u64 ltmask = ((u64)1 << lane) - 1;

    u64 b0[8], b1[8];
#pragma unroll
    for (int e = 0; e < 8; e++) {
        b0[e] = __ballot(es.x == e);
        b1[e] = __ballot(es.y == e);
    }
    if (lane < 8) {
        u64 m0 = b0[0], m1 = b1[0];
#pragma unroll
        for (int e = 1; e < 8; e++) {
            if (lane == e) { m0 = b0[e]; m1 = b1[e]; }
        }
        wcnt[w][lane] = __popcll(m0) + __popcll(m1);
    }
    __syncthreads();
    if (tid < 8) {
        int tot = wcnt[0][tid] + wcnt[1][tid] + wcnt[2][tid] + wcnt[3][tid];
        gbase[tid] = atomicAdd(&counts[tid * CSTR], tot);
    }
    __syncthreads();

    // per-lane ballot select for own experts
    u64 my0 = b0[0], my1a = b0[0], my1b = b1[0];
#pragma unroll
    for (int e = 1; e < 8; e++) {
        if (es.x == e) my0 = b0[e];
        if (es.y == e) { my1a = b0[e]; my1b = b1[e]; }
    }
    int wb0 = gbase[es.x], wb1 = gbase[es.y];
#pragma unroll
    for (int ww = 0; ww < 4; ww++) {
        if (ww < w) { wb0 += wcnt[ww][es.x]; wb1 += wcnt[ww][es.y]; }
    }
    int pos0 = wb0 + __popcll(my0 & ltmask);
    int pos1 = wb1 + __popcll(my1a) + __popcll(my1b & ltmask);
    list[es.x * T_TOK + pos0] = t; wlist[es.x * T_TOK + pos0] = ws.x;
    list[es.y * T_TOK + pos1] = t; wlist[es.y * T_TOK + pos1] = ws.y;
    p01[t] = make_int2(pos0, pos1);
}

__global__ void k_base(const int* __restrict__ counts, int* __restrict__ base) {
    int b = 0;
    for (int e = 0; e < 8; e++) { base[e] = b; b += counts[e * CSTR]; }
    base[8] = b;
}

// ---------------- weight prep: W1[e] = [gate;up;loraA] bf16, K=2048 ----------------
__global__ __launch_bounds__(256) void k_w1(
    const float* __restrict__ gate_w, const float* __restrict__ up_w,
    const float* __restrict__ lora_A, u16* __restrict__ W1)
{
    int idx = (blockIdx.x * 256 + threadIdx.x) * 4;
    int e = idx / (N1 * H_DIM);
    int rem = idx - e * (N1 * H_DIM);
    int r = rem / H_DIM;
    int h = rem - r * H_DIM;
    const float* src;
    if (r < 256)      src = gate_w + ((size_t)(e * 256 + r) * H_DIM + h);
    else if (r < 512) src = up_w   + ((size_t)(e * 256 + (r - 256)) * H_DIM + h);
    else              src = lora_A + ((size_t)(e * 16 + (r - 512)) * H_DIM + h);
    float4 v = *reinterpret_cast<const float4*>(src);
    ushort4 o; o.x = f2bf(v.x); o.y = f2bf(v.y); o.z = f2bf(v.z); o.w = f2bf(v.w);
    *reinterpret_cast<ushort4*>(W1 + idx) = o;
}

// ---------------- weight prep: W2[e][h] = [down(256)|loraB(16)|0(16)] bf16 ----------------
__global__ __launch_bounds__(256) void k_w2(
    const float* __restrict__ down_w, const float* __restrict__ lora_B,
    u16* __restrict__ W2)
{
    int idx = (blockIdx.x * 256 + threadIdx.x) * 4;
    int e = idx / (H_DIM * K2);
    int rem = idx - e * (H_DIM * K2);
    int h = rem / K2;
    int c = rem - h * K2;
    ushort4 o;
    if (c < 256) {
        float4 v = *reinterpret_cast<const float4*>(down_w + ((size_t)(e * H_DIM + h) * 256 + c));
        o.x = f2bf(v.x); o.y = f2bf(v.y); o.z = f2bf(v.z); o.w = f2bf(v.w);
    } else if (c < 272) {
        float4 v = *reinterpret_cast<const float4*>(lora_B + ((size_t)(e * H_DIM + h) * 16 + (c - 256)));
        o.x = f2bf(v.x); o.y = f2bf(v.y); o.z = f2bf(v.z); o.w = f2bf(v.w);
    } else {
        o.x = 0; o.y = 0; o.z = 0; o.w = 0;
    }
    *reinterpret_cast<ushort4*>(W2 + idx) = o;
}

// ---------------- stage A: m97-style 128x128 tile, LDS staged, silu fused ----------------
// grid.x = 2048 linear: s = bid&31 (e = s>>2, nt = s&3), mt = bid>>5 (0..63)
// B-tile rows (128) = [gate f0-31][up f0-31][gate f32-63][up f32-63], f rel to nt*64.
// XOR chunk swizzle: LDS[row][c] holds global chunk c^(row&7); read chunk j at c=j^(row&7).
__global__ __launch_bounds__(256, 2) void k_stage_a(
    const u16* __restrict__ xbf, const u16* __restrict__ W1,
    const int* __restrict__ counts, const int* __restrict__ base,
    const int* __restrict__ list, u16* __restrict__ ascr)
{
    int bid = blockIdx.x;
    int s = bid & 31, mt = bid >> 5;
    int e = s >> 2, nt = s & 3;
    int ne = counts[e * CSTR];
    int m0 = mt * 128;
    if (m0 >= ne) return;

    __shared__ u16 lA[128 * 64];   // 16 KB
    __shared__ u16 lB[128 * 64];   // 16 KB
    __shared__ u16 lL[16 * 64];    // 2 KB (loraA rows)

    const int L = threadIdx.x;
    int w = L >> 6, l = L & 63;
    int wm = w >> 1, wn = w & 1;
    int r16 = l & 15, q = l >> 4;
    int sr = L >> 3, sc = L & 7;           // staging: row-within-group, chunk

    const u16* w1e = W1 + (size_t)e * N1 * H_DIM;
    const u16* aptr[4]; const u16* bptr[4];
#pragma unroll
    for (int a = 0; a < 4; a++) {
        int row = a * 32 + sr;
        int pos = m0 + row; if (pos >= ne) pos = ne - 1;
        int t = list[e * T_TOK + pos];
        aptr[a] = xbf + (size_t)t * H_DIM + (sc ^ (sr & 7)) * 8;
        int w1row = (a & 1) * 256 + nt * 64 + (a >> 1) * 32 + sr;
        bptr[a] = w1e + (size_t)w1row * H_DIM + (sc ^ (sr & 7)) * 8;
    }
    bool lora_blk = (nt == 0);
    const u16* lptr = nullptr;
    if (lora_blk && w < 2) {
        int row = L >> 3;                  // 0..15
        lptr = w1e + (size_t)(512 + row) * H_DIM + (sc ^ (row & 7)) * 8;
    }
    bool lora_wave = lora_blk && (wn == 0);

    f32x4 acc[4][4] = {};                  // [mi][ni]; ni 0,1 gate / 2,3 up
    f32x4 accl[4] = {};

    for (int r = 0; r < 32; ++r) {
        int k0 = r * 64;
        __syncthreads();
#pragma unroll
        for (int a = 0; a < 4; a++) {
            gl16(aptr[a] + k0, &lA[(a * 256 + L) * 8]);
            gl16(bptr[a] + k0, &lB[(a * 256 + L) * 8]);
        }
        if (lora_blk && w < 2) gl16(lptr + k0, &lL[L * 8]);
        __syncthreads();
#pragma unroll
        for (int ks = 0; ks < 2; ks++) {
            bf16x8 af[4], bfr[4];
#pragma unroll
            for (int mi = 0; mi < 4; mi++) {
                int row = wm * 64 + mi * 16 + r16;
                af[mi] = *reinterpret_cast<const bf16x8*>(&lA[(row * 8 + ((ks * 4 + q) ^ (row & 7))) * 8]);
            }
#pragma unroll
            for (int ni = 0; ni < 4; ni++) {
                int rb = wn * 64 + ni * 16 + r16;
                bfr[ni] = *reinterpret_cast<const bf16x8*>(&lB[(rb * 8 + ((ks * 4 + q) ^ (rb & 7))) * 8]);
            }
#pragma unroll
            for (int mi = 0; mi < 4; mi++)
#pragma unroll
                for (int ni = 0; ni < 4; ni++)
                    acc[mi][ni] = __builtin_amdgcn_mfma_f32_16x16x32_bf16(af[mi], bfr[ni], acc[mi][ni], 0, 0, 0);
            if (lora_wave) {
                bf16x8 lf = *reinterpret_cast<const bf16x8*>(&lL[(r16 * 8 + ((ks * 4 + q) ^ (r16 & 7))) * 8]);
#pragma unroll
                for (int mi = 0; mi < 4; mi++)
                    accl[mi] = __builtin_amdgcn_mfma_f32_16x16x32_bf16(af[mi], lf, accl[mi], 0, 0, 0);
            }
        }
    }

    int eb = base[e];
#pragma unroll
    for (int mi = 0; mi < 4; mi++)
#pragma unroll
        for (int reg = 0; reg < 4; reg++) {
            int pos = m0 + wm * 64 + mi * 16 + q * 4 + reg;
            if (pos >= ne) continue;
            size_t ro = (size_t)(eb + pos) * K2;
#pragma unroll
            for (int ni = 0; ni < 2; ni++) {
                float g = acc[mi][ni][reg], u = acc[mi][ni + 2][reg];
                float val = g / (1.f + __expf(-g)) * u;          // silu(g)*u
                ascr[ro + nt * 64 + wn * 32 + ni * 16 + r16] = f2bf(val);
            }
            if (lora_wave) {
                ascr[ro + 256 + r16] = f2bf(accl[mi][reg]);
                ascr[ro + 272 + r16] = 0;                        // K-pad
            }
        }
}

// ---------------- stage B: 128x128 tile, K=288 in 3 rounds of BK=96 ----------------
// grid.x = 8192 linear: s = bid&127 (e = s>>4, ntile = s&15), mt = bid>>7 (0..63)
// chunk swizzle on low 2 bits: LDS[row][c] holds global chunk (c&~3)|((c&3)^(row&3)).
template <bool USE_Y>
__global__ __launch_bounds__(256, 2) void k_stage_b(
    const u16* __restrict__ ascr, const u16* __restrict__ W2,
    const int* __restrict__ counts, const int* __restrict__ base,
    const int* __restrict__ list, const float* __restrict__ wlist,
    u16* __restrict__ Y, float* __restrict__ out)
{
    int bid = blockIdx.x;
    int s = bid & 127, mt = bid >> 7;
    int e = s >> 4, ntile = s & 15;
    int ne = counts[e * CSTR];
    int m0 = mt * 128;
    if (m0 >= ne) return;
    int n0 = ntile * 128;

    __shared__ u16 lA[128 * 96];   // 24 KB
    __shared__ u16 lB[128 * 96];   // 24 KB

    const int L = threadIdx.x;
    int w = L >> 6, l = L & 63;
    int wm = w >> 1, wn = w & 1;
    int r16 = l & 15, q = l >> 4;
    int eb = base[e];

    const u16* w2e = W2 + (size_t)e * H_DIM * K2;
    const u16* aptr[6]; const u16* bptr[6];
#pragma unroll
    for (int a = 0; a < 6; a++) {
        int g = a * 256 + L;                 // 0..1535 chunks (128 rows x 12)
        int row = g / 12, c = g - row * 12;
        int csw = (c & ~3) | ((c & 3) ^ (row & 3));
        int pos = m0 + row; if (pos >= ne) pos = ne - 1;
        aptr[a] = ascr + (size_t)(eb + pos) * K2 + csw * 8;
        bptr[a] = w2e + (size_t)(n0 + row) * K2 + csw * 8;
    }

    f32x4 acc[4][4] = {};
    for (int r = 0; r < 3; ++r) {
        int k0 = r * 96;
        __syncthreads();
#pragma unroll
        for (int a = 0; a < 6; a++) {
            gl16(aptr[a] + k0, &lA[(a * 256 + L) * 8]);
            gl16(bptr[a] + k0, &lB[(a * 256 + L) * 8]);
        }
        __syncthreads();
#pragma unroll
        for (int ks = 0; ks < 3; ks++) {
            bf16x8 af[4], bfr[4];
#pragma unroll
            for (int mi = 0; mi < 4; mi++) {
                int row = wm * 64 + mi * 16 + r16;
                int j = ks * 4 + (q ^ (row & 3));
                af[mi] = *reinterpret_cast<const bf16x8*>(&lA[(row * 12 + j) * 8]);
            }
#pragma unroll
            for (int ni = 0; ni < 4; ni++) {
                int rb = wn * 64 + ni * 16 + r16;
                int j = ks * 4 + (q ^ (rb & 3));
                bfr[ni] = *reinterpret_cast<const bf16x8*>(&lB[(rb * 12 + j) * 8]);
            }
#pragma unroll
            for (int mi = 0; mi < 4; mi++)
#pragma unroll
                for (int ni = 0; ni < 4; ni++)
                    acc[mi][ni] = __builtin_amdgcn_mfma_f32_16x16x32_bf16(af[mi], bfr[ni], acc[mi][ni], 0, 0, 0);
        }
    }

#pragma unroll
    for (int mi = 0; mi < 4; mi++)
#pragma unroll
        for (int reg = 0; reg < 4; reg++) {
            int pos = m0 + wm * 64 + mi * 16 + q * 4 + reg;
            if (pos >= ne) continue;
            if (USE_Y) {
                size_t ro = (size_t)(eb + pos) * H_DIM;
#pragma unroll
                for (int ni = 0; ni < 4; ni++)
                    Y[ro + n0 + wn * 64 + ni * 16 + r16] = f2bf(acc[mi][ni][reg]);
            } else {
                int t = list[e * T_TOK + pos];
                float wt = wlist[e * T_TOK + pos];
#pragma unroll
                for (int ni = 0; ni < 4; ni++)
                    atomicAdd(out + (size_t)t * H_DIM + n0 + wn * 64 + ni * 16 + r16, wt * acc[mi][ni][reg]);
            }
        }
}

// ---------------- combine: out[t] = w0*Y[s0] + w1*Y[s1] ----------------
__global__ __launch_bounds__(256) void k_combine(
    const u16* __restrict__ Y, const int* __restrict__ base,
    const int2* __restrict__ e01, const int2* __restrict__ p01,
    const float2* __restrict__ w01, float* __restrict__ out)
{
    int t = blockIdx.x;
    int c = threadIdx.x * 8;
    int2 es = e01[t]; int2 ps = p01[t]; float2 ws = w01[t];
    size_t s0 = (size_t)(base[es.x] + ps.x) * H_DIM + c;
    size_t s1 = (size_t)(base[es.y] + ps.y) * H_DIM + c;
    u16x8 a = *reinterpret_cast<const u16x8*>(Y + s0);
    u16x8 b = *reinterpret_cast<const u16x8*>(Y + s1);
    float* op = out + (size_t)t * H_DIM + c;
    float4 o0, o1;
    o0.x = ws.x * bf2f(a[0]) + ws.y * bf2f(b[0]);
    o0.y = ws.x * bf2f(a[1]) + ws.y * bf2f(b[1]);
    o0.z = ws.x * bf2f(a[2]) + ws.y * bf2f(b[2]);
    o0.w = ws.x * bf2f(a[3]) + ws.y * bf2f(b[3]);
    o1.x = ws.x * bf2f(a[4]) + ws.y * bf2f(b[4]);
    o1.y = ws.x * bf2f(a[5]) + ws.y * bf2f(b[5]);
    o1.z = ws.x * bf2f(a[6]) + ws.y * bf2f(b[6]);
    o1.w = ws.x * bf2f(a[7]) + ws.y * bf2f(b[7]);
    *reinterpret_cast<float4*>(op) = o0;
    *reinterpret_cast<float4*>(op + 4) = o1;
}

extern "C" void kernel_launch(void* const* d_in, const int* in_sizes, int n_in,
                              void* d_out, int out_size, void* d_ws, size_t ws_size,
                              hipStream_t stream)
{
    const float* x      = (const float*)d_in[0];
    const float* G      = (const float*)d_in[1];
    const float* gate_w = (const float*)d_in[2];
    const float* up_w   = (const float*)d_in[3];
    const float* down_w = (const float*)d_in[4];
    const float* lora_A = (const float*)d_in[5];
    const float* lora_B = (const float*)d_in[6];
    float* out = (float*)d_out;

    char* ws = (char*)d_ws;
    size_t o = 0;
    auto carve = [&](size_t bytes) -> char* {
        char* p = ws + o;
        o = (o + bytes + 255) & ~(size_t)255;
        return p;
    };
    int*    counts = (int*)carve(8 * CSTR * 4);
    int*    ebase  = (int*)carve(9 * 4);
    float*  Gt     = (float*)carve((size_t)E_NUM * H_DIM * 4);
    int2*   e01    = (int2*)carve((size_t)T_TOK * 8);
    int2*   p01    = (int2*)carve((size_t)T_TOK * 8);
    float2* w01    = (float2*)carve((size_t)T_TOK * 8);
    int*    list   = (int*)carve((size_t)E_NUM * T_TOK * 4);
    float*  wlist  = (float*)carve((size_t)E_NUM * T_TOK * 4);
    u16*    xbf    = (u16*)carve((size_t)T_TOK * H_DIM * 2);
    u16*    W1     = (u16*)carve((size_t)E_NUM * N1 * H_DIM * 2);
    u16*    W2     = (u16*)carve((size_t)E_NUM * H_DIM * K2 * 2);
    u16*    ascr   = (u16*)carve((size_t)2 * T_TOK * K2 * 2);
    u16*    Y      = (u16*)carve((size_t)2 * T_TOK * H_DIM * 2);
    bool use_y = (ws_size >= o);

    hipMemsetAsync(counts, 0, 8 * CSTR * 4, stream);
    k_gt<<<(E_NUM * H_DIM) / 256, 256, 0, stream>>>(G, Gt);
    k_router<<<T_TOK / 4, 256, 0, stream>>>(x, Gt, xbf, e01, w01);
    k_count<<<T_TOK / 256, 256, 0, stream>>>(e01, w01, counts, list, wlist, p01);
    k_base<<<1, 1, 0, stream>>>(counts, ebase);
    k_w1<<<(E_NUM * N1 * H_DIM / 4) / 256, 256, 0, stream>>>(gate_w, up_w, lora_A, W1);
    k_w2<<<(E_NUM * H_DIM * K2 / 4) / 256, 256, 0, stream>>>(down_w, lora_B, W2);
    k_stage_a<<<2048, 256, 0, stream>>>(xbf, W1, counts, ebase, list, ascr);
    if (use_y) {
        k_stage_b<true><<<8192, 256, 0, stream>>>(ascr, W2, counts, ebase, list, wlist, Y, out);
        k_combine<<<T_TOK, 256, 0, stream>>>(Y, ebase, e01, p01, w01, out);
    } else {
        hipMemsetAsync(out, 0, (size_t)out_size * 4, stream);
        k_stage_b<false><<<8192, 256, 0, stream>>>(ascr, W2, counts, ebase, list, wlist, Y, out);
    }
}